// Round 6
// baseline (728.475 us; speedup 1.0000x reference)
//
#include <hip/hip_runtime.h>
#include <stdint.h>

#define NN 50000
#define DEG 16
#define MT 32
#define NBLK ((NN + MT - 1) / MT)
#define LOG2E 1.4426950408889634f

typedef short bf16x8 __attribute__((ext_vector_type(8)));
typedef float f32x4 __attribute__((ext_vector_type(4)));
typedef unsigned short u16;
typedef unsigned int u32;

static __device__ __forceinline__ u16 f2bf(float f) {
  union { float f; u32 u; } v; v.f = f;
  u32 u = v.u + 0x7FFFu + ((v.u >> 16) & 1u);   // round-to-nearest-even
  return (u16)(u >> 16);
}
static __device__ __forceinline__ float rcp_(float x) {
  return __builtin_amdgcn_rcpf(x);
}
static __device__ __forceinline__ float ex2_(float x) {
  return __builtin_amdgcn_exp2f(x);
}

// ---------------------------------------------------------------------------
// Prep: bf16-convert x, prepack MFMA B-fragments (8-wave layout), bias sums.
// Gate weights/biases PRE-SCALED by log2e (i,f,o) / 2*log2e (g) so the
// elementwise phase uses raw v_exp_f32 (exp2) directly.
// ---------------------------------------------------------------------------
__global__ void k_prep(const float* __restrict__ x, u16* __restrict__ xb,
                       const float* __restrict__ wih1, const float* __restrict__ whh1, u16* __restrict__ wpk1,
                       const float* __restrict__ wih2, const float* __restrict__ whh2, u16* __restrict__ wpk2,
                       const float* __restrict__ lr1, const float* __restrict__ ll1, u16* __restrict__ epk1,
                       const float* __restrict__ lr2, const float* __restrict__ ll2, u16* __restrict__ epk2,
                       const float* __restrict__ linw, u16* __restrict__ hpk,
                       const float* __restrict__ bi1, const float* __restrict__ bh1, float* __restrict__ bs1,
                       const float* __restrict__ bi2, const float* __restrict__ bh2, float* __restrict__ bs2) {
  int b = blockIdx.x;
  if (b < 128) {
    const float* wih = (b < 64) ? wih1 : wih2;
    const float* whh = (b < 64) ? whh1 : whh2;
    u16* wpk = (b < 64) ? wpk1 : wpk2;
    int t = (b & 63) * 256 + threadIdx.x;          // 0..16383
    int lane = t & 63, kt = (t >> 6) & 7, g = (t >> 9) & 3, w = (t >> 11) & 7;
    int col = g * 128 + w * 16 + (lane & 15);
    int k0 = kt * 32 + (lane >> 4) * 8;
    float sc = (g == 2) ? 2.f * LOG2E : LOG2E;
#pragma unroll
    for (int j = 0; j < 8; ++j) {
      int k = k0 + j;
      float v = (k < 128) ? wih[col * 128 + k] : whh[col * 128 + k - 128];
      wpk[t * 8 + j] = f2bf(sc * v);
    }
  } else if (b < 160) {
    // epilogue weights: k<128 lin_r (over x), k>=128 lin_l (over h) — unscaled
    const float* lrw = (b < 144) ? lr1 : lr2;
    const float* llw = (b < 144) ? ll1 : ll2;
    u16* epk = (b < 144) ? epk1 : epk2;
    int t = ((b - 128) & 15) * 256 + threadIdx.x;  // 0..4095
    int lane = t & 63, kt = (t >> 6) & 7, w = (t >> 9) & 7;
    int col = w * 16 + (lane & 15);
    int k0 = kt * 32 + (lane >> 4) * 8;
#pragma unroll
    for (int j = 0; j < 8; ++j) {
      int k = k0 + j;
      epk[t * 8 + j] = f2bf(k < 128 ? lrw[col * 128 + k] : llw[col * 128 + k - 128]);
    }
  } else if (b < 164) {
    // head weights [64,128], waves 0..3 — unscaled
    int t = (b - 160) * 256 + threadIdx.x;         // 0..1023
    int lane = t & 63, kt = (t >> 6) & 3, w = (t >> 8) & 3;
    int col = w * 16 + (lane & 15);
    int k0 = kt * 32 + (lane >> 4) * 8;
#pragma unroll
    for (int j = 0; j < 8; ++j) hpk[t * 8 + j] = f2bf(linw[col * 128 + k0 + j]);
  } else if (b < 168) {
    int t = (b - 164) * 256 + threadIdx.x;         // 0..1023
    if (t < 1024) {
      int i = t & 511;
      float sc = ((i >> 7) == 2) ? 2.f * LOG2E : LOG2E;
      if (t < 512) bs1[i] = sc * (bi1[i] + bh1[i]);
      else bs2[i] = sc * (bi2[i] + bh2[i]);
    }
  } else {
    int i = (b - 168) * 256 + threadIdx.x;
    int stride = (gridDim.x - 168) * 256;
    for (; i < NN * 128 / 4; i += stride) {
      float4 v = ((const float4*)x)[i];
      ushort4 o;
      o.x = f2bf(v.x); o.y = f2bf(v.y); o.z = f2bf(v.z); o.w = f2bf(v.w);
      ((ushort4*)xb)[i] = o;
    }
  }
}

// ---------------------------------------------------------------------------
// Fused SAGE-LSTM layer, v6: 512 threads = 8 waves, MT=32 nodes/block.
// KEY CHANGE vs v4: x-part A-fragments are loaded DIRECTLY from global into
// registers (per-lane gather == exact 16x16x32 A-frag: lane reads 16B at
// xin[idx*128 + lh*8 + kt*32]). All 8 waves read the same 8KB/step -> L1
// serves 7/8. Removes AX LDS staging + its vmcnt/barrier coupling and halves
// LDS read traffic. Step order: h-part(s) -> issue x-loads(s+1) -> EW(s)
// (covers load latency) -> x-part(s+1) -> barrier (protects only AH).
// Single acc set (EW(s) precedes x-part(s+1)) -> no spills (v5 lesson).
// LDS XOR-swizzle on AH: byte ^= (row&15)<<4.
// ---------------------------------------------------------------------------

#define XLOAD(DCODE)                                                          \
  do {                                                                        \
    int i0_, i1_;                                                             \
    if ((DCODE) < DEG) {                                                      \
      i0_ = IDX[lr * DEG + (DCODE)];                                          \
      i1_ = IDX[(16 + lr) * DEG + (DCODE)];                                   \
    } else {                                                                  \
      int n0_ = node0 + lr, n1_ = node0 + 16 + lr;                            \
      i0_ = (n0_ < NN) ? n0_ : NN - 1;                                        \
      i1_ = (n1_ < NN) ? n1_ : NN - 1;                                        \
    }                                                                         \
    const u16* b0_ = xin + (size_t)i0_ * 128 + lh * 8;                        \
    const u16* b1_ = xin + (size_t)i1_ * 128 + lh * 8;                        \
    _Pragma("unroll") for (int kt = 0; kt < 4; ++kt) {                        \
      xf0[kt] = *(const bf16x8*)(b0_ + kt * 32);                              \
      xf1[kt] = *(const bf16x8*)(b1_ + kt * 32);                              \
    }                                                                         \
  } while (0)

#define XPART()                                                               \
  do {                                                                        \
    _Pragma("unroll") for (int g = 0; g < 4; ++g) {                           \
      acc0[g] = (f32x4){gb[g], gb[g], gb[g], gb[g]};                          \
      acc1[g] = (f32x4){gb[g], gb[g], gb[g], gb[g]};                          \
    }                                                                         \
    _Pragma("unroll") for (int kt = 0; kt < 4; ++kt) {                        \
      _Pragma("unroll") for (int g = 0; g < 4; ++g) {                         \
        acc0[g] = __builtin_amdgcn_mfma_f32_16x16x32_bf16(xf0[kt], wreg[g][kt], acc0[g], 0, 0, 0); \
        acc1[g] = __builtin_amdgcn_mfma_f32_16x16x32_bf16(xf1[kt], wreg[g][kt], acc1[g], 0, 0, 0); \
      }                                                                       \
    }                                                                         \
  } while (0)

#define HPART(AHSRC)                                                          \
  do {                                                                        \
    _Pragma("unroll") for (int kt = 0; kt < 4; ++kt) {                        \
      bf16x8 af0 = *(const bf16x8*)((const char*)(AHSRC) + lr * 256 +         \
                                    ((kt * 64 + lh * 16) ^ ((lr & 15) << 4))); \
      bf16x8 af1 = *(const bf16x8*)((const char*)(AHSRC) + (16 + lr) * 256 +  \
                                    ((kt * 64 + lh * 16) ^ ((lr & 15) << 4))); \
      _Pragma("unroll") for (int g = 0; g < 4; ++g) {                         \
        acc0[g] = __builtin_amdgcn_mfma_f32_16x16x32_bf16(af0, wreg[g][4 + kt], acc0[g], 0, 0, 0); \
        acc1[g] = __builtin_amdgcn_mfma_f32_16x16x32_bf16(af1, wreg[g][4 + kt], acc1[g], 0, 0, 0); \
      }                                                                       \
    }                                                                         \
  } while (0)

#define GATE_EW(AHDST)                                                        \
  do {                                                                        \
    _Pragma("unroll") for (int mt = 0; mt < 2; ++mt)                          \
        _Pragma("unroll") for (int r = 0; r < 4; ++r) {                       \
      float a0 = mt ? acc1[0][r] : acc0[0][r];                                \
      float a1 = mt ? acc1[1][r] : acc0[1][r];                                \
      float a2 = mt ? acc1[2][r] : acc0[2][r];                                \
      float a3 = mt ? acc1[3][r] : acc0[3][r];                                \
      float iv = rcp_(1.f + ex2_(-a0));                                       \
      float fv = rcp_(1.f + ex2_(-a1));                                       \
      float gv = 1.f - 2.f * rcp_(1.f + ex2_(a2));                            \
      float ov = rcp_(1.f + ex2_(-a3));                                       \
      float cv = fv * c[mt][r] + iv * gv;                                     \
      c[mt][r] = cv;                                                          \
      float th = 1.f - 2.f * rcp_(1.f + ex2_(2.f * LOG2E * cv));              \
      int row = mt * 16 + lh * 4 + r;                                         \
      int jj = 2 * (w * 16 + lr);                                             \
      *(u16*)((char*)(AHDST) + row * 256 + (jj ^ ((row & 15) << 4))) =        \
          f2bf(ov * th);                                                      \
    }                                                                         \
  } while (0)

template <int L2>
__global__ __launch_bounds__(512, 2) void k_layer(
    const u16* __restrict__ xin, const int* __restrict__ src,
    const u16* __restrict__ wpk, const float* __restrict__ bsum,
    const u16* __restrict__ epk, const float* __restrict__ linlb,
    u16* __restrict__ hout, const u16* __restrict__ hpk,
    const float* __restrict__ linb, float* __restrict__ dout) {
  __shared__ __align__(16) u16 AH[2][MT * 128];   // 2 x 8 KB
  __shared__ int IDX[MT * DEG];                   // 2 KB

  const int tid = threadIdx.x;
  const int w = tid >> 6, l = tid & 63;
  const int lr = l & 15, lh = l >> 4;
  const int node0 = blockIdx.x * MT;

  // ---- register-resident weight panel: 32 frags = 128 VGPRs, loaded ONCE ----
  bf16x8 wreg[4][8];
#pragma unroll
  for (int g = 0; g < 4; ++g)
#pragma unroll
    for (int kt = 0; kt < 8; ++kt)
      wreg[g][kt] = *(const bf16x8*)(wpk + (size_t)(((w * 4 + g) * 8 + kt) * 64 + l) * 8);

  IDX[tid] = (node0 + (tid >> 4) < NN) ? src[node0 * DEG + tid] : 0;

  float gb[4];
#pragma unroll
  for (int g = 0; g < 4; ++g) gb[g] = bsum[g * 128 + w * 16 + lr];
  __syncthreads();  // IDX ready

  bf16x8 xf0[4], xf1[4];
  f32x4 acc0[4], acc1[4];
  f32x4 c[2];
  c[0] = (f32x4){0.f, 0.f, 0.f, 0.f};
  c[1] = (f32x4){0.f, 0.f, 0.f, 0.f};

  // prologue: x-frags(0) from global, x-part(0)
  XLOAD(0);
  XPART();

#pragma unroll 1
  for (int step = 0; step < DEG; ++step) {
    const int cb = step & 1, nb = cb ^ 1;

    if (step) HPART(AH[cb]);   // h-part(s), gated by prev-iter barrier
    XLOAD(step + 1);           // issue x gather for s+1 (own-x at s=15)
    GATE_EW(AH[nb]);           // trans-heavy; covers gather latency
    if (step < DEG - 1) XPART();  // x-part(s+1): regs only, no LDS hazard
    __syncthreads();           // protects AH[nb] handoff only
  }

  // Epilogue: out = lin_r(x_own) + lin_l(h_final) + b, ReLU.
  // xf holds own-x frags (loaded at step 15); AH[0] holds final h.
  float eb = linlb[w * 16 + lr];
  f32x4 eacc[2];
  eacc[0] = (f32x4){eb, eb, eb, eb};
  eacc[1] = (f32x4){eb, eb, eb, eb};
#pragma unroll
  for (int kt = 0; kt < 4; ++kt) {
    bf16x8 bf = *(const bf16x8*)(epk + (size_t)((w * 8 + kt) * 64 + l) * 8);
    eacc[0] = __builtin_amdgcn_mfma_f32_16x16x32_bf16(xf0[kt], bf, eacc[0], 0, 0, 0);
    eacc[1] = __builtin_amdgcn_mfma_f32_16x16x32_bf16(xf1[kt], bf, eacc[1], 0, 0, 0);
  }
#pragma unroll
  for (int kt = 0; kt < 4; ++kt) {
    bf16x8 af[2];
#pragma unroll
    for (int mt = 0; mt < 2; ++mt) {
      int row = mt * 16 + lr;
      af[mt] = *(const bf16x8*)((const char*)AH[0] + row * 256 +
                                ((kt * 64 + lh * 16) ^ ((row & 15) << 4)));
    }
    bf16x8 bf = *(const bf16x8*)(epk + (size_t)((w * 8 + 4 + kt) * 64 + l) * 8);
#pragma unroll
    for (int mt = 0; mt < 2; ++mt)
      eacc[mt] = __builtin_amdgcn_mfma_f32_16x16x32_bf16(af[mt], bf, eacc[mt], 0, 0, 0);
  }

  if constexpr (!L2) {
#pragma unroll
    for (int mt = 0; mt < 2; ++mt)
#pragma unroll
      for (int r = 0; r < 4; ++r) {
        int node = node0 + mt * 16 + lh * 4 + r;
        if (node < NN) {
          float v = fmaxf(eacc[mt][r], 0.f);
          hout[(size_t)node * 128 + w * 16 + lr] = f2bf(v);
        }
      }
  } else {
    // stash relu(h2) into AH[1] (free), then fused 128->64 head (waves 0..3)
#pragma unroll
    for (int mt = 0; mt < 2; ++mt)
#pragma unroll
      for (int r = 0; r < 4; ++r) {
        int row = mt * 16 + lh * 4 + r;
        float v = fmaxf(eacc[mt][r], 0.f);
        int jj = 2 * (w * 16 + lr);
        *(u16*)((char*)AH[1] + row * 256 + (jj ^ ((row & 15) << 4))) = f2bf(v);
      }
    __syncthreads();
    if (w < 4) {
      float hb = linb[w * 16 + lr];
      f32x4 hacc[2];
      hacc[0] = (f32x4){hb, hb, hb, hb};
      hacc[1] = (f32x4){hb, hb, hb, hb};
#pragma unroll
      for (int kt = 0; kt < 4; ++kt) {
        bf16x8 af[2];
#pragma unroll
        for (int mt = 0; mt < 2; ++mt) {
          int row = mt * 16 + lr;
          af[mt] = *(const bf16x8*)((const char*)AH[1] + row * 256 +
                                    ((kt * 64 + lh * 16) ^ ((row & 15) << 4)));
        }
        bf16x8 bf = *(const bf16x8*)(hpk + (size_t)((w * 4 + kt) * 64 + l) * 8);
#pragma unroll
        for (int mt = 0; mt < 2; ++mt)
          hacc[mt] = __builtin_amdgcn_mfma_f32_16x16x32_bf16(af[mt], bf, hacc[mt], 0, 0, 0);
      }
#pragma unroll
      for (int mt = 0; mt < 2; ++mt)
#pragma unroll
        for (int r = 0; r < 4; ++r) {
          int node = node0 + mt * 16 + lh * 4 + r;
          if (node < NN) dout[(size_t)node * 64 + w * 16 + lr] = hacc[mt][r];
        }
    }
  }
}

extern "C" void kernel_launch(void* const* d_in, const int* in_sizes, int n_in,
                              void* d_out, int out_size, void* d_ws, size_t ws_size,
                              hipStream_t stream) {
  const float* x    = (const float*)d_in[0];
  const int*   edge = (const int*)d_in[1];   // src = first N*DEG entries
  const float* wih1 = (const float*)d_in[2];
  const float* whh1 = (const float*)d_in[3];
  const float* bih1 = (const float*)d_in[4];
  const float* bhh1 = (const float*)d_in[5];
  const float* ll1w = (const float*)d_in[6];
  const float* ll1b = (const float*)d_in[7];
  const float* lr1w = (const float*)d_in[8];
  const float* wih2 = (const float*)d_in[9];
  const float* whh2 = (const float*)d_in[10];
  const float* bih2 = (const float*)d_in[11];
  const float* bhh2 = (const float*)d_in[12];
  const float* ll2w = (const float*)d_in[13];
  const float* ll2b = (const float*)d_in[14];
  const float* lr2w = (const float*)d_in[15];
  const float* linw = (const float*)d_in[16];
  const float* linb = (const float*)d_in[17];

  char* ws = (char*)d_ws;
  u16* xb    = (u16*)(ws);                       // 12,800,000 B
  u16* h1b   = (u16*)(ws + 12800000);            // 12,800,000 B
  u16* wpk1  = (u16*)(ws + 25600000);            //    262,144 B
  u16* wpk2  = (u16*)(ws + 25862144);            //    262,144 B
  u16* epk1  = (u16*)(ws + 26124288);            //     65,536 B
  u16* epk2  = (u16*)(ws + 26189824);            //     65,536 B
  u16* hpk   = (u16*)(ws + 26255360);            //     16,384 B
  float* bs1 = (float*)(ws + 26271744);          //      2,048 B
  float* bs2 = (float*)(ws + 26273792);          //      2,048 B

  k_prep<<<1000, 256, 0, stream>>>(x, xb,
                                   wih1, whh1, wpk1, wih2, whh2, wpk2,
                                   lr1w, ll1w, epk1, lr2w, ll2w, epk2,
                                   linw, hpk,
                                   bih1, bhh1, bs1, bih2, bhh2, bs2);
  k_layer<0><<<NBLK, 512, 0, stream>>>(xb, edge, wpk1, bs1, epk1, ll1b,
                                       h1b, nullptr, nullptr, nullptr);
  k_layer<1><<<NBLK, 512, 0, stream>>>(h1b, edge, wpk2, bs2, epk2, ll2b,
                                       nullptr, hpk, linb, (float*)d_out);
}

// Round 7
// 529.982 us; speedup vs baseline: 1.3745x; 1.3745x over previous
//
#include <hip/hip_runtime.h>
#include <stdint.h>

#define NN 50000
#define DEG 16
#define MT 32
#define NBLK ((NN + MT - 1) / MT)
#define LOG2E 1.4426950408889634f

typedef short bf16x8 __attribute__((ext_vector_type(8)));
typedef float f32x4 __attribute__((ext_vector_type(4)));
typedef unsigned short u16;
typedef unsigned int u32;

static __device__ __forceinline__ u16 f2bf(float f) {
  union { float f; u32 u; } v; v.f = f;
  u32 u = v.u + 0x7FFFu + ((v.u >> 16) & 1u);   // round-to-nearest-even
  return (u16)(u >> 16);
}
static __device__ __forceinline__ float rcp_(float x) {
  return __builtin_amdgcn_rcpf(x);
}
static __device__ __forceinline__ float ex2_(float x) {
  return __builtin_amdgcn_exp2f(x);
}
static __device__ __forceinline__ void gload_lds16(const void* g, void* l) {
  __builtin_amdgcn_global_load_lds(
      (const __attribute__((address_space(1))) void*)g,
      (__attribute__((address_space(3))) void*)l, 16, 0, 0);
}

// ---------------------------------------------------------------------------
// Prep: bf16-convert x, prepack MFMA B-fragments (8-wave layout), bias sums.
// Gate weights/biases PRE-SCALED by log2e (i,f,o) / 2*log2e (g) so the
// elementwise phase uses raw v_exp_f32 (exp2) directly.
// ---------------------------------------------------------------------------
__global__ void k_prep(const float* __restrict__ x, u16* __restrict__ xb,
                       const float* __restrict__ wih1, const float* __restrict__ whh1, u16* __restrict__ wpk1,
                       const float* __restrict__ wih2, const float* __restrict__ whh2, u16* __restrict__ wpk2,
                       const float* __restrict__ lr1, const float* __restrict__ ll1, u16* __restrict__ epk1,
                       const float* __restrict__ lr2, const float* __restrict__ ll2, u16* __restrict__ epk2,
                       const float* __restrict__ linw, u16* __restrict__ hpk,
                       const float* __restrict__ bi1, const float* __restrict__ bh1, float* __restrict__ bs1,
                       const float* __restrict__ bi2, const float* __restrict__ bh2, float* __restrict__ bs2) {
  int b = blockIdx.x;
  if (b < 128) {
    const float* wih = (b < 64) ? wih1 : wih2;
    const float* whh = (b < 64) ? whh1 : whh2;
    u16* wpk = (b < 64) ? wpk1 : wpk2;
    int t = (b & 63) * 256 + threadIdx.x;          // 0..16383
    int lane = t & 63, kt = (t >> 6) & 7, g = (t >> 9) & 3, w = (t >> 11) & 7;
    int col = g * 128 + w * 16 + (lane & 15);
    int k0 = kt * 32 + (lane >> 4) * 8;
    float sc = (g == 2) ? 2.f * LOG2E : LOG2E;
#pragma unroll
    for (int j = 0; j < 8; ++j) {
      int k = k0 + j;
      float v = (k < 128) ? wih[col * 128 + k] : whh[col * 128 + k - 128];
      wpk[t * 8 + j] = f2bf(sc * v);
    }
  } else if (b < 160) {
    // epilogue weights: k<128 lin_r (over x), k>=128 lin_l (over h) — unscaled
    const float* lrw = (b < 144) ? lr1 : lr2;
    const float* llw = (b < 144) ? ll1 : ll2;
    u16* epk = (b < 144) ? epk1 : epk2;
    int t = ((b - 128) & 15) * 256 + threadIdx.x;  // 0..4095
    int lane = t & 63, kt = (t >> 6) & 7, w = (t >> 9) & 7;
    int col = w * 16 + (lane & 15);
    int k0 = kt * 32 + (lane >> 4) * 8;
#pragma unroll
    for (int j = 0; j < 8; ++j) {
      int k = k0 + j;
      epk[t * 8 + j] = f2bf(k < 128 ? lrw[col * 128 + k] : llw[col * 128 + k - 128]);
    }
  } else if (b < 164) {
    // head weights [64,128], waves 0..3 — unscaled
    int t = (b - 160) * 256 + threadIdx.x;         // 0..1023
    int lane = t & 63, kt = (t >> 6) & 3, w = (t >> 8) & 3;
    int col = w * 16 + (lane & 15);
    int k0 = kt * 32 + (lane >> 4) * 8;
#pragma unroll
    for (int j = 0; j < 8; ++j) hpk[t * 8 + j] = f2bf(linw[col * 128 + k0 + j]);
  } else if (b < 168) {
    int t = (b - 164) * 256 + threadIdx.x;         // 0..1023
    if (t < 1024) {
      int i = t & 511;
      float sc = ((i >> 7) == 2) ? 2.f * LOG2E : LOG2E;
      if (t < 512) bs1[i] = sc * (bi1[i] + bh1[i]);
      else bs2[i] = sc * (bi2[i] + bh2[i]);
    }
  } else {
    int i = (b - 168) * 256 + threadIdx.x;
    int stride = (gridDim.x - 168) * 256;
    for (; i < NN * 128 / 4; i += stride) {
      float4 v = ((const float4*)x)[i];
      ushort4 o;
      o.x = f2bf(v.x); o.y = f2bf(v.y); o.z = f2bf(v.z); o.w = f2bf(v.w);
      ((ushort4*)xb)[i] = o;
    }
  }
}

// ---------------------------------------------------------------------------
// Fused SAGE-LSTM layer, v7 = v4 + counted-vmcnt barrier (T4) + 2-ahead gather.
// v4 facts: 0 bank conflicts, no spills, 321us/layer, but __syncthreads()'s
// implicit vmcnt(0) drained the just-issued random gather EVERY step (m97
// lesson). v7: AX triple-buffered; step s issues gather(s+2); barrier is
//   s_waitcnt vmcnt(1) lgkmcnt(0); s_barrier
// -> drains only gather(s+1) (issued a full step earlier, latency hidden),
// keeps gather(s+2) in flight across the barrier.
// LDS XOR-swizzle: byte ^= (row&15)<<4.  Wave w owns gate cols [16w,16w+16).
// ---------------------------------------------------------------------------

#define GATHER(DCODE, PDST)                                                   \
  do {                                                                        \
    int idx_;                                                                 \
    if ((DCODE) < DEG) idx_ = IDX[grow * DEG + (DCODE)];                      \
    else idx_ = (node0 + grow < NN) ? node0 + grow : NN - 1;                  \
    const char* gsw_ = (const char*)(xin + (size_t)idx_ * 128) +              \
                       ((lr * 16) ^ ((grow & 15) << 4));                      \
    gload_lds16(gsw_, (PDST) + (w * 4) * 128);                                \
  } while (0)

#define CBAR(N)                                                               \
  do {                                                                        \
    asm volatile("s_waitcnt vmcnt(" #N ") lgkmcnt(0)" ::: "memory");          \
    __builtin_amdgcn_s_barrier();                                             \
    __builtin_amdgcn_sched_barrier(0);                                        \
  } while (0)

template <int L2>
__global__ __launch_bounds__(512, 2) void k_layer(
    const u16* __restrict__ xin, const int* __restrict__ src,
    const u16* __restrict__ wpk, const float* __restrict__ bsum,
    const u16* __restrict__ epk, const float* __restrict__ linlb,
    u16* __restrict__ hout, const u16* __restrict__ hpk,
    const float* __restrict__ linb, float* __restrict__ dout) {
  __shared__ __align__(16) u16 AX[3][MT * 128];   // 3 x 8 KB (triple buffer)
  __shared__ __align__(16) u16 AH[2][MT * 128];   // 2 x 8 KB
  __shared__ int IDX[MT * DEG];                   // 2 KB

  const int tid = threadIdx.x;
  const int w = tid >> 6, l = tid & 63;
  const int lr = l & 15, lh = l >> 4;
  const int node0 = blockIdx.x * MT;
  const int grow = w * 4 + lh;  // this lane's gather row

  // ---- register-resident weight panel: 32 frags = 128 VGPRs, loaded ONCE ----
  bf16x8 wreg[4][8];
#pragma unroll
  for (int g = 0; g < 4; ++g)
#pragma unroll
    for (int kt = 0; kt < 8; ++kt)
      wreg[g][kt] = *(const bf16x8*)(wpk + (size_t)(((w * 4 + g) * 8 + kt) * 64 + l) * 8);

  IDX[tid] = (node0 + (tid >> 4) < NN) ? src[node0 * DEG + tid] : 0;

  float gb[4];
#pragma unroll
  for (int g = 0; g < 4; ++g) gb[g] = bsum[g * 128 + w * 16 + lr];
  float eb = linlb[w * 16 + lr];
  __syncthreads();  // IDX ready; vmcnt fully drained (baseline 0 outstanding)

  // prologue: gather x_0 -> AX[0], x_1 -> AX[1] (2 outstanding)
  GATHER(0, AX[0]);
  GATHER(1, AX[1]);

  f32x4 c[2];
  c[0] = (f32x4){0.f, 0.f, 0.f, 0.f};
  c[1] = (f32x4){0.f, 0.f, 0.f, 0.f};
  CBAR(1);  // x_0 landed; x_1 still in flight

  u16 *pA = AX[0], *pB = AX[1], *pC = AX[2];

#pragma unroll 1
  for (int step = 0; step < DEG; ++step) {
    const int cb = step & 1, nb = cb ^ 1;

    // issue gather(step+2) into the free buffer (d=16 -> own features)
    if (step < DEG - 1) GATHER(step + 2, pC);

    // acc init = gate bias (pre-scaled): free bias add via MFMA C-in
    f32x4 acc[2][4];
#pragma unroll
    for (int mt = 0; mt < 2; ++mt)
#pragma unroll
      for (int g = 0; g < 4; ++g)
        acc[mt][g] = (f32x4){gb[g], gb[g], gb[g], gb[g]};

    // x-part of gates: K tiles 0..3 (A from AX[pA], B from registers)
#pragma unroll
    for (int kt = 0; kt < 4; ++kt) {
      bf16x8 af[2];
#pragma unroll
      for (int mt = 0; mt < 2; ++mt) {
        int row = mt * 16 + lr;
        af[mt] = *(const bf16x8*)((const char*)pA + row * 256 +
                                  ((kt * 64 + lh * 16) ^ ((row & 15) << 4)));
      }
#pragma unroll
      for (int g = 0; g < 4; ++g)
#pragma unroll
        for (int mt = 0; mt < 2; ++mt)
          acc[mt][g] = __builtin_amdgcn_mfma_f32_16x16x32_bf16(af[mt], wreg[g][kt], acc[mt][g], 0, 0, 0);
    }

    // h-part of gates: K tiles 4..7 (h == 0 at step 0)
    if (step) {
#pragma unroll
      for (int kt = 0; kt < 4; ++kt) {
        bf16x8 af[2];
#pragma unroll
        for (int mt = 0; mt < 2; ++mt) {
          int row = mt * 16 + lr;
          af[mt] = *(const bf16x8*)((const char*)AH[cb] + row * 256 +
                                    ((kt * 64 + lh * 16) ^ ((row & 15) << 4)));
        }
#pragma unroll
        for (int g = 0; g < 4; ++g)
#pragma unroll
          for (int mt = 0; mt < 2; ++mt)
            acc[mt][g] = __builtin_amdgcn_mfma_f32_16x16x32_bf16(af[mt], wreg[g][4 + kt], acc[mt][g], 0, 0, 0);
      }
    }

    // LSTM elementwise (exp2 domain); write new h (bf16) into AH[nb]
#pragma unroll
    for (int mt = 0; mt < 2; ++mt)
#pragma unroll
      for (int r = 0; r < 4; ++r) {
        float iv = rcp_(1.f + ex2_(-acc[mt][0][r]));
        float fv = rcp_(1.f + ex2_(-acc[mt][1][r]));
        float gv = 1.f - 2.f * rcp_(1.f + ex2_(acc[mt][2][r]));
        float ov = rcp_(1.f + ex2_(-acc[mt][3][r]));
        float cv = fv * c[mt][r] + iv * gv;
        c[mt][r] = cv;
        float th = 1.f - 2.f * rcp_(1.f + ex2_(2.f * LOG2E * cv));
        int row = mt * 16 + lh * 4 + r;
        int jj = 2 * (w * 16 + lr);
        *(u16*)((char*)AH[nb] + row * 256 + (jj ^ ((row & 15) << 4))) =
            f2bf(ov * th);
      }

    // counted barrier: drain gather(step+1) only; keep gather(step+2) flying
    if (step < DEG - 1) CBAR(1);
    else CBAR(0);  // last step: drain the own-x gather for the epilogue

    u16* t_ = pA; pA = pB; pB = t_; 
    t_ = pB; pB = pC; pC = t_;  // rotate: pA<-pB, pB<-pC, pC<-old pA
  }

  // Epilogue: out = lin_r(x_own) + lin_l(h_final) + b, ReLU.
  // After 16 rotations pA holds the d=16 buffer (own x); AH[0] the final h.
  f32x4 eacc[2];
  eacc[0] = (f32x4){eb, eb, eb, eb};
  eacc[1] = (f32x4){eb, eb, eb, eb};
#pragma unroll
  for (int kt = 0; kt < 8; ++kt) {
    const u16* srcb = (kt < 4) ? pA : AH[0];
    int kb = (kt & 3) * 64 + lh * 16;
    bf16x8 af[2];
#pragma unroll
    for (int mt = 0; mt < 2; ++mt) {
      int row = mt * 16 + lr;
      af[mt] = *(const bf16x8*)((const char*)srcb + row * 256 +
                                (kb ^ ((row & 15) << 4)));
    }
    bf16x8 bf = *(const bf16x8*)(epk + (size_t)((w * 8 + kt) * 64 + l) * 8);
#pragma unroll
    for (int mt = 0; mt < 2; ++mt)
      eacc[mt] = __builtin_amdgcn_mfma_f32_16x16x32_bf16(af[mt], bf, eacc[mt], 0, 0, 0);
  }

  if constexpr (!L2) {
#pragma unroll
    for (int mt = 0; mt < 2; ++mt)
#pragma unroll
      for (int r = 0; r < 4; ++r) {
        int node = node0 + mt * 16 + lh * 4 + r;
        if (node < NN) {
          float v = fmaxf(eacc[mt][r], 0.f);
          hout[(size_t)node * 128 + w * 16 + lr] = f2bf(v);
        }
      }
  } else {
    // stash relu(h2) into AH[1] (free), then fused 128->64 head (waves 0..3)
#pragma unroll
    for (int mt = 0; mt < 2; ++mt)
#pragma unroll
      for (int r = 0; r < 4; ++r) {
        int row = mt * 16 + lh * 4 + r;
        float v = fmaxf(eacc[mt][r], 0.f);
        int jj = 2 * (w * 16 + lr);
        *(u16*)((char*)AH[1] + row * 256 + (jj ^ ((row & 15) << 4))) = f2bf(v);
      }
    __syncthreads();
    if (w < 4) {
      float hb = linb[w * 16 + lr];
      f32x4 hacc[2];
      hacc[0] = (f32x4){hb, hb, hb, hb};
      hacc[1] = (f32x4){hb, hb, hb, hb};
#pragma unroll
      for (int kt = 0; kt < 4; ++kt) {
        bf16x8 af[2];
#pragma unroll
        for (int mt = 0; mt < 2; ++mt) {
          int row = mt * 16 + lr;
          af[mt] = *(const bf16x8*)((const char*)AH[1] + row * 256 +
                                    ((kt * 64 + lh * 16) ^ ((row & 15) << 4)));
        }
        bf16x8 bf = *(const bf16x8*)(hpk + (size_t)((w * 4 + kt) * 64 + l) * 8);
#pragma unroll
        for (int mt = 0; mt < 2; ++mt)
          hacc[mt] = __builtin_amdgcn_mfma_f32_16x16x32_bf16(af[mt], bf, hacc[mt], 0, 0, 0);
      }
#pragma unroll
      for (int mt = 0; mt < 2; ++mt)
#pragma unroll
        for (int r = 0; r < 4; ++r) {
          int node = node0 + mt * 16 + lh * 4 + r;
          if (node < NN) dout[(size_t)node * 64 + w * 16 + lr] = hacc[mt][r];
        }
    }
  }
}

extern "C" void kernel_launch(void* const* d_in, const int* in_sizes, int n_in,
                              void* d_out, int out_size, void* d_ws, size_t ws_size,
                              hipStream_t stream) {
  const float* x    = (const float*)d_in[0];
  const int*   edge = (const int*)d_in[1];   // src = first N*DEG entries
  const float* wih1 = (const float*)d_in[2];
  const float* whh1 = (const float*)d_in[3];
  const float* bih1 = (const float*)d_in[4];
  const float* bhh1 = (const float*)d_in[5];
  const float* ll1w = (const float*)d_in[6];
  const float* ll1b = (const float*)d_in[7];
  const float* lr1w = (const float*)d_in[8];
  const float* wih2 = (const float*)d_in[9];
  const float* whh2 = (const float*)d_in[10];
  const float* bih2 = (const float*)d_in[11];
  const float* bhh2 = (const float*)d_in[12];
  const float* ll2w = (const float*)d_in[13];
  const float* ll2b = (const float*)d_in[14];
  const float* lr2w = (const float*)d_in[15];
  const float* linw = (const float*)d_in[16];
  const float* linb = (const float*)d_in[17];

  char* ws = (char*)d_ws;
  u16* xb    = (u16*)(ws);                       // 12,800,000 B
  u16* h1b   = (u16*)(ws + 12800000);            // 12,800,000 B
  u16* wpk1  = (u16*)(ws + 25600000);            //    262,144 B
  u16* wpk2  = (u16*)(ws + 25862144);            //    262,144 B
  u16* epk1  = (u16*)(ws + 26124288);            //     65,536 B
  u16* epk2  = (u16*)(ws + 26189824);            //     65,536 B
  u16* hpk   = (u16*)(ws + 26255360);            //     16,384 B
  float* bs1 = (float*)(ws + 26271744);          //      2,048 B
  float* bs2 = (float*)(ws + 26273792);          //      2,048 B

  k_prep<<<1000, 256, 0, stream>>>(x, xb,
                                   wih1, whh1, wpk1, wih2, whh2, wpk2,
                                   lr1w, ll1w, epk1, lr2w, ll2w, epk2,
                                   linw, hpk,
                                   bih1, bhh1, bs1, bih2, bhh2, bs2);
  k_layer<0><<<NBLK, 512, 0, stream>>>(xb, edge, wpk1, bs1, epk1, ll1b,
                                       h1b, nullptr, nullptr, nullptr);
  k_layer<1><<<NBLK, 512, 0, stream>>>(h1b, edge, wpk2, bs2, epk2, ll2b,
                                       nullptr, hpk, linb, (float*)d_out);
}